// Round 3
// baseline (1646.313 us; speedup 1.0000x reference)
//
#include <hip/hip_runtime.h>

#define NPTS   300000
#define NPAIRS 100000
#define KOFF   27
#define CIN    32
#define COUT   64
#define NGROUP 8
#define EPSV   1e-5f
#define SLOPE  0.01f

#define NTOT   (KOFF * NPAIRS)                 // 2.7M pairs
#define BINSZ  64                              // out-rows per bin (16KB LDS tile)
#define BINSH  6
#define NBIN   ((NPTS + BINSZ - 1) / BINSZ)    // 4688
#define NSEG   (KOFF * NBIN)                   // 126576 segments; seg = bin*KOFF + k

// workspace (ints): statsP[256] | segCount[NSEG] | segStart[NSEG] | segCursor[NSEG] | sorted[NTOT]
#define WS_INTS_NEEDED (256 + 3 * NSEG + NTOT)

// ---------------------------------------------------------------- zero metadata
__global__ __launch_bounds__(256) void zero_meta_kernel(int* __restrict__ segCount,
                                                        float* __restrict__ statsP) {
    int i = blockIdx.x * 256 + threadIdx.x;
    if (i < NSEG) segCount[i] = 0;
    if (i < 256) statsP[i] = 0.f;
}

// ---------------------------------------------------------------- histogram over (bin,k)
__global__ __launch_bounds__(256) void hist_kernel(const int* __restrict__ out_idx,
                                                   int* __restrict__ segCount) {
    int g = blockIdx.x * 256 + threadIdx.x;
    if (g >= NTOT) return;
    int rout = out_idx[g];
    int key = (rout >> BINSH) * KOFF + (g / NPAIRS);
    atomicAdd(&segCount[key], 1);
}

// ---------------------------------------------------------------- exclusive scan (1 block)
__global__ __launch_bounds__(1024) void scan_kernel(const int* __restrict__ cnt,
                                                    int* __restrict__ start,
                                                    int* __restrict__ cursor) {
    __shared__ int part[1024];
    const int t = threadIdx.x;
    const int per = (NSEG + 1023) / 1024;      // 124
    int lo = t * per;
    int hi = lo + per; if (hi > NSEG) hi = NSEG;
    int s = 0;
    for (int i = lo; i < hi; ++i) s += cnt[i];
    part[t] = s;
    __syncthreads();
    for (int off = 1; off < 1024; off <<= 1) {
        int v = (t >= off) ? part[t - off] : 0;
        __syncthreads();
        part[t] += v;
        __syncthreads();
    }
    int run = (t == 0) ? 0 : part[t - 1];
    for (int i = lo; i < hi; ++i) {
        start[i] = run; cursor[i] = run;
        run += cnt[i];
    }
}

// ---------------------------------------------------------------- scatter into segment lists
// entry = (rout_local[6b] << 19) | rin[19b]; (bin,k) implicit in segment id
__global__ __launch_bounds__(256) void scatter_kernel(const int* __restrict__ out_idx,
                                                      const int* __restrict__ in_idx,
                                                      int* __restrict__ segCursor,
                                                      int* __restrict__ sorted) {
    int g = blockIdx.x * 256 + threadIdx.x;
    if (g >= NTOT) return;
    int rout = out_idx[g];
    int rin  = in_idx[g];
    int key = (rout >> BINSH) * KOFF + (g / NPAIRS);
    int pos = atomicAdd(&segCursor[key], 1);
    sorted[pos] = ((rout & (BINSZ - 1)) << 19) | rin;
}

// ---------------------------------------------------------------- binned conv + fused stats
// One block (4 waves, 256 thr) per 64-row out bin; 16KB LDS tile -> 8 blocks/CU (full TLP).
// Wave wv handles k = wv, wv+4, ... ; W[k][:,lane] in 32 VGPRs.
// Entries bulk-loaded per-lane (vector) and __shfl-broadcast: per-pair memory chain is ONLY
// the wave-uniform feats-row s_load (SMEM is OOO -> lgkmcnt(0) -> no SW pipelining; TLP hides).
// LDS atomic accumulate; single coalesced flush per row; group stats fused into the flush.
__global__ __launch_bounds__(256) void conv_binned_kernel(
    const float* __restrict__ feats, const float* __restrict__ weight,
    const int* __restrict__ sorted, const int* __restrict__ segStart,
    const int* __restrict__ segCount, float* __restrict__ out,
    float* __restrict__ statsP)
{
    __shared__ float accS[BINSZ * COUT];       // 16KB
    __shared__ float sm_s[4][NGROUP];
    __shared__ float sm_ss[4][NGROUP];
    const int bin  = blockIdx.x;
    const int lane = threadIdx.x & 63;
    const int wv   = threadIdx.x >> 6;         // 0..3

    for (int i = threadIdx.x; i < BINSZ * COUT; i += 256) accS[i] = 0.f;
    __syncthreads();

    for (int k = wv; k < KOFF; k += 4) {
        const int s   = bin * KOFF + k;
        const int st  = segStart[s];
        const int len = segCount[s];
        if (len <= 0) continue;

        float w[CIN];
        const float* wk = weight + k * (CIN * COUT) + lane;
#pragma unroll
        for (int i = 0; i < CIN; ++i) w[i] = wk[i * COUT];

        for (int c0 = 0; c0 < len; c0 += 64) {
            int nn = len - c0; if (nn > 64) nn = 64;
            int ent = (lane < nn) ? sorted[st + c0 + lane] : 0;   // one coalesced vector load
            for (int j = 0; j < nn; ++j) {
                int e  = __builtin_amdgcn_readfirstlane(__shfl(ent, j, 64)); // no mem op
                const float* f = feats + (size_t)(e & 0x7FFFF) * CIN;        // SGPR row load
                int rl = e >> 19;
                float a0 = 0.f, a1 = 0.f;
#pragma unroll
                for (int i = 0; i < CIN; i += 2) {
                    a0 = fmaf(f[i],     w[i],     a0);
                    a1 = fmaf(f[i + 1], w[i + 1], a1);
                }
                atomicAdd(&accS[rl * COUT + lane], a0 + a1);      // ds_add, fire-and-forget
            }
        }
    }
    __syncthreads();

    // flush (each out row written exactly once -> no zero pass) + fused group stats
    float s = 0.f, ss = 0.f;
    const int base = bin << BINSH;
    for (int r = wv; r < BINSZ; r += 4) {
        int row = base + r;
        if (row < NPTS) {
            float v = accS[r * COUT + lane];
            out[(size_t)row * COUT + lane] = v;
            s += v; ss += v * v;
        }
    }
    // reduce 8 lanes of each channel-group (g = lane>>3)
    s += __shfl_xor(s, 1, 64);  ss += __shfl_xor(ss, 1, 64);
    s += __shfl_xor(s, 2, 64);  ss += __shfl_xor(ss, 2, 64);
    s += __shfl_xor(s, 4, 64);  ss += __shfl_xor(ss, 4, 64);
    if ((lane & 7) == 0) { sm_s[wv][lane >> 3] = s; sm_ss[wv][lane >> 3] = ss; }
    __syncthreads();
    if (threadIdx.x < 16) {
        int g = threadIdx.x & 7;
        bool isss = threadIdx.x >= 8;
        float t = 0.f;
#pragma unroll
        for (int wvi = 0; wvi < 4; ++wvi) t += isss ? sm_ss[wvi][g] : sm_s[wvi][g];
        // padded: one 64B line per counter -> no same-line RMW serialization
        atomicAdd(statsP + (isss ? (8 + g) * 16 : g * 16), t);
    }
}

// ---------------------------------------------------------------- fallback path kernels
#define PAIRS_PER_BLOCK 256
#define BLOCKS_PER_K ((NPAIRS + PAIRS_PER_BLOCK - 1) / PAIRS_PER_BLOCK)  // 391

__global__ __launch_bounds__(256) void zero_kernel(float4* __restrict__ out4, int n4,
                                                   float* __restrict__ stats) {
    int i = blockIdx.x * blockDim.x + threadIdx.x;
    if (i < n4) out4[i] = make_float4(0.f, 0.f, 0.f, 0.f);
    if (blockIdx.x == 0 && threadIdx.x < 16) stats[threadIdx.x] = 0.f;
}

__global__ __launch_bounds__(256) void conv_kernel(
    const float* __restrict__ feats, const float* __restrict__ weight,
    const int* __restrict__ in_idx, const int* __restrict__ out_idx,
    float* __restrict__ out)
{
    const int lane = threadIdx.x & 63;
    const int wave = threadIdx.x >> 6;
    const int k     = blockIdx.x / BLOCKS_PER_K;
    const int pair0 = (blockIdx.x % BLOCKS_PER_K) * PAIRS_PER_BLOCK;

    float w[CIN];
    const float* wk = weight + k * (CIN * COUT) + lane;
#pragma unroll
    for (int i = 0; i < CIN; ++i) w[i] = wk[i * COUT];

    const int per_wave = PAIRS_PER_BLOCK / 4;
    int p    = pair0 + wave * per_wave;
    int pend = p + per_wave;
    if (pend > NPAIRS) pend = NPAIRS;

    const int* ii = in_idx  + k * NPAIRS;
    const int* oi = out_idx + k * NPAIRS;

    for (; p < pend; ++p) {
        int rin  = __builtin_amdgcn_readfirstlane(ii[p]);
        int rout = __builtin_amdgcn_readfirstlane(oi[p]);
        const float* frow = feats + (size_t)rin * CIN;
        float acc = 0.f;
#pragma unroll
        for (int i = 0; i < CIN; ++i)
            acc = fmaf(frow[i], w[i], acc);
        atomicAdd(out + (size_t)rout * COUT + lane, acc);
    }
}

__global__ __launch_bounds__(256) void stats_kernel(const float4* __restrict__ out4,
                                                    float* __restrict__ stats) {
    const int tid  = blockIdx.x * 256 + threadIdx.x;
    const int ntid = gridDim.x * 256;
    const int n4   = NPTS * COUT / 4;

    float s = 0.f, ss = 0.f;
    for (int i = tid; i < n4; i += ntid) {
        float4 v = out4[i];
        s  += v.x + v.y + v.z + v.w;
        ss += v.x * v.x + v.y * v.y + v.z * v.z + v.w * v.w;
    }
    s  += __shfl_xor(s,  1, 64);  ss += __shfl_xor(ss,  1, 64);
    s  += __shfl_xor(s, 16, 64);  ss += __shfl_xor(ss, 16, 64);
    s  += __shfl_xor(s, 32, 64);  ss += __shfl_xor(ss, 32, 64);

    __shared__ float sm_s[4][NGROUP];
    __shared__ float sm_ss[4][NGROUP];
    const int lane = threadIdx.x & 63;
    const int wv   = threadIdx.x >> 6;
    if (lane < 16 && (lane & 1) == 0) {
        sm_s [wv][lane >> 1] = s;
        sm_ss[wv][lane >> 1] = ss;
    }
    __syncthreads();
    if (threadIdx.x < NGROUP) {
        float ts = 0.f, tss = 0.f;
#pragma unroll
        for (int wvi = 0; wvi < 4; ++wvi) { ts += sm_s[wvi][threadIdx.x]; tss += sm_ss[wvi][threadIdx.x]; }
        atomicAdd(stats + threadIdx.x,          ts);
        atomicAdd(stats + NGROUP + threadIdx.x, tss);
    }
}

// ---------------------------------------------------------------- normalize + affine + leaky relu
// sstride: element stride between group counters (16 = padded main path, 1 = fallback)
__global__ __launch_bounds__(256) void norm_kernel(float4* __restrict__ out4, int n4,
                                                   const float* __restrict__ stats,
                                                   const float* __restrict__ gamma,
                                                   const float* __restrict__ beta,
                                                   int sstride) {
    int i = blockIdx.x * blockDim.x + threadIdx.x;
    if (i >= n4) return;
    int c0 = (i & 15) * 4;
    int g  = c0 >> 3;
    const float cnt = (float)NPTS * (COUT / NGROUP);
    float mean = stats[g * sstride] / cnt;
    float var  = stats[(8 + g) * sstride] / cnt - mean * mean;
    float inv  = rsqrtf(var + EPSV);
    float4 v  = out4[i];
    float4 ga = *(const float4*)(gamma + c0);
    float4 be = *(const float4*)(beta  + c0);
    float x;
    x = (v.x - mean) * inv * ga.x + be.x; v.x = x >= 0.f ? x : SLOPE * x;
    x = (v.y - mean) * inv * ga.y + be.y; v.y = x >= 0.f ? x : SLOPE * x;
    x = (v.z - mean) * inv * ga.z + be.z; v.z = x >= 0.f ? x : SLOPE * x;
    x = (v.w - mean) * inv * ga.w + be.w; v.w = x >= 0.f ? x : SLOPE * x;
    out4[i] = v;
}

// ---------------------------------------------------------------- launch
extern "C" void kernel_launch(void* const* d_in, const int* in_sizes, int n_in,
                              void* d_out, int out_size, void* d_ws, size_t ws_size,
                              hipStream_t stream) {
    const float* feats  = (const float*)d_in[0];
    const float* weight = (const float*)d_in[1];
    const float* gamma  = (const float*)d_in[2];
    const float* beta   = (const float*)d_in[3];
    const int*   in_idx = (const int*)d_in[4];
    const int*   out_idx= (const int*)d_in[5];
    float* out   = (float*)d_out;

    int n4 = out_size / 4;                 // 4.8M float4
    int zb = (n4 + 255) / 256;

    if (ws_size >= (size_t)WS_INTS_NEEDED * 4) {
        float* statsP   = (float*)d_ws;
        int* segCount   = (int*)d_ws + 256;
        int* segStart   = segCount + NSEG;
        int* segCursor  = segStart + NSEG;
        int* sorted     = segCursor + NSEG;

        int pb = (NTOT + 255) / 256;       // 10547
        zero_meta_kernel<<<(NSEG + 255) / 256, 256, 0, stream>>>(segCount, statsP);
        hist_kernel<<<pb, 256, 0, stream>>>(out_idx, segCount);
        scan_kernel<<<1, 1024, 0, stream>>>(segCount, segStart, segCursor);
        scatter_kernel<<<pb, 256, 0, stream>>>(out_idx, in_idx, segCursor, sorted);
        conv_binned_kernel<<<NBIN, 256, 0, stream>>>(feats, weight, sorted,
                                                     segStart, segCount, out, statsP);
        norm_kernel<<<zb, 256, 0, stream>>>((float4*)out, n4, statsP, gamma, beta, 16);
    } else {
        // fallback: proven atomic path
        float* stats = (float*)d_ws;
        zero_kernel<<<zb, 256, 0, stream>>>((float4*)out, n4, stats);
        conv_kernel<<<KOFF * BLOCKS_PER_K, 256, 0, stream>>>(feats, weight, in_idx, out_idx, out);
        stats_kernel<<<2048, 256, 0, stream>>>((const float4*)out, stats);
        norm_kernel<<<zb, 256, 0, stream>>>((float4*)out, n4, stats, gamma, beta, 1);
    }
}

// Round 4
// 760.986 us; speedup vs baseline: 2.1634x; 2.1634x over previous
//
#include <hip/hip_runtime.h>

#define NPTS   300000
#define NPAIRS 100000
#define KOFF   27
#define CIN    32
#define COUT   64
#define NGROUP 8
#define EPSV   1e-5f
#define SLOPE  0.01f

#define PAIRS_PER_BLOCK 256
#define BLOCKS_PER_K ((NPAIRS + PAIRS_PER_BLOCK - 1) / PAIRS_PER_BLOCK)  // 391

// ---------------------------------------------------------------- zero
__global__ __launch_bounds__(256) void zero_kernel(float4* __restrict__ out4, int n4,
                                                   float* __restrict__ stats) {
    int i = blockIdx.x * blockDim.x + threadIdx.x;
    if (i < n4) out4[i] = make_float4(0.f, 0.f, 0.f, 0.f);
    if (blockIdx.x == 0 && threadIdx.x < 16) stats[threadIdx.x] = 0.f;
}

// ---------------------------------------------------------------- conv (gather-matmul-scatter)
// One wave streams pairs of one kernel offset k. lane = output channel c.
// W[k][:,c] is loaded ONCE and PINNED into 32 VGPRs via an empty inline-asm
// "+v" barrier: rounds 0-3 all showed VGPR_Count < 32, i.e. the compiler was
// rematerializing these loads inside the pair loop -> 8KB of L1 traffic per
// pair (84 MB per CU = ~550 us wall, the measured 570-578 us plateau).
// Pair row indices are wave-uniform (readfirstlane) -> feats row is a scalar
// (SMEM) load; frow[i] feeds v_fmac as the single SGPR operand.
__global__ __launch_bounds__(256) void conv_kernel(
    const float* __restrict__ feats, const float* __restrict__ weight,
    const int* __restrict__ in_idx, const int* __restrict__ out_idx,
    float* __restrict__ out)
{
    const int lane = threadIdx.x & 63;
    const int wave = threadIdx.x >> 6;
    const int k     = blockIdx.x / BLOCKS_PER_K;
    const int pair0 = (blockIdx.x % BLOCKS_PER_K) * PAIRS_PER_BLOCK;

    float w[CIN];
    const float* wk = weight + k * (CIN * COUT) + lane;
#pragma unroll
    for (int i = 0; i < CIN; ++i) w[i] = wk[i * COUT];
    // Force each w[i] to live in a VGPR; the loads above can no longer be
    // folded/rematerialized into the pair loop.
#pragma unroll
    for (int i = 0; i < CIN; ++i) asm volatile("" : "+v"(w[i]));

    const int per_wave = PAIRS_PER_BLOCK / 4;         // 64 pairs per wave
    int p    = pair0 + wave * per_wave;
    int pend = p + per_wave;
    if (pend > NPAIRS) pend = NPAIRS;

    const int* ii = in_idx  + k * NPAIRS;
    const int* oi = out_idx + k * NPAIRS;

    for (; p < pend; ++p) {
        int rin  = __builtin_amdgcn_readfirstlane(ii[p]);   // wave-uniform
        int rout = __builtin_amdgcn_readfirstlane(oi[p]);
        const float* frow = feats + (size_t)rin * CIN;
        // 4 accumulator chains: dep-latency (4cyc) fully hidden behind issue.
        float a0 = 0.f, a1 = 0.f, a2 = 0.f, a3 = 0.f;
#pragma unroll
        for (int i = 0; i < CIN; i += 4) {
            a0 = fmaf(frow[i],     w[i],     a0);
            a1 = fmaf(frow[i + 1], w[i + 1], a1);
            a2 = fmaf(frow[i + 2], w[i + 2], a2);
            a3 = fmaf(frow[i + 3], w[i + 3], a3);
        }
        atomicAdd(out + (size_t)rout * COUT + lane, (a0 + a1) + (a2 + a3));
    }
}

// ---------------------------------------------------------------- group stats (sum, sumsq)
// float4 per thread; channel block (i&15)*4 is constant per thread since the
// grid stride is a multiple of 16. Wave shuffle-reduce -> LDS -> 16 atomics/block.
__global__ __launch_bounds__(256) void stats_kernel(const float4* __restrict__ out4,
                                                    float* __restrict__ stats) {
    const int tid  = blockIdx.x * 256 + threadIdx.x;
    const int ntid = gridDim.x * 256;                 // multiple of 16
    const int n4   = NPTS * COUT / 4;

    float s = 0.f, ss = 0.f;
    for (int i = tid; i < n4; i += ntid) {
        float4 v = out4[i];
        s  += v.x + v.y + v.z + v.w;
        ss += v.x * v.x + v.y * v.y + v.z * v.z + v.w * v.w;
    }
    // group of this thread's float4: g = (lane&15)>>1, same for lanes l^1, l^16, l^32
    s  += __shfl_xor(s,  1, 64);  ss += __shfl_xor(ss,  1, 64);
    s  += __shfl_xor(s, 16, 64);  ss += __shfl_xor(ss, 16, 64);
    s  += __shfl_xor(s, 32, 64);  ss += __shfl_xor(ss, 32, 64);

    __shared__ float sm_s[4][NGROUP];
    __shared__ float sm_ss[4][NGROUP];
    const int lane = threadIdx.x & 63;
    const int wv   = threadIdx.x >> 6;
    if (lane < 16 && (lane & 1) == 0) {
        sm_s [wv][lane >> 1] = s;
        sm_ss[wv][lane >> 1] = ss;
    }
    __syncthreads();
    if (threadIdx.x < NGROUP) {
        float ts = 0.f, tss = 0.f;
#pragma unroll
        for (int wvi = 0; wvi < 4; ++wvi) { ts += sm_s[wvi][threadIdx.x]; tss += sm_ss[wvi][threadIdx.x]; }
        atomicAdd(stats + threadIdx.x,          ts);
        atomicAdd(stats + NGROUP + threadIdx.x, tss);
    }
}

// ---------------------------------------------------------------- normalize + affine + leaky relu
__global__ __launch_bounds__(256) void norm_kernel(float4* __restrict__ out4, int n4,
                                                   const float* __restrict__ stats,
                                                   const float* __restrict__ gamma,
                                                   const float* __restrict__ beta) {
    int i = blockIdx.x * blockDim.x + threadIdx.x;
    if (i >= n4) return;
    int c0 = (i & 15) * 4;              // first channel of this float4; stays in one group
    int g  = c0 >> 3;
    const float cnt = (float)NPTS * (COUT / NGROUP);
    float mean = stats[g] / cnt;
    float var  = stats[8 + g] / cnt - mean * mean;
    float inv  = rsqrtf(var + EPSV);
    float4 v  = out4[i];
    float4 ga = *(const float4*)(gamma + c0);
    float4 be = *(const float4*)(beta  + c0);
    float x;
    x = (v.x - mean) * inv * ga.x + be.x; v.x = x >= 0.f ? x : SLOPE * x;
    x = (v.y - mean) * inv * ga.y + be.y; v.y = x >= 0.f ? x : SLOPE * x;
    x = (v.z - mean) * inv * ga.z + be.z; v.z = x >= 0.f ? x : SLOPE * x;
    x = (v.w - mean) * inv * ga.w + be.w; v.w = x >= 0.f ? x : SLOPE * x;
    out4[i] = v;
}

// ---------------------------------------------------------------- launch
extern "C" void kernel_launch(void* const* d_in, const int* in_sizes, int n_in,
                              void* d_out, int out_size, void* d_ws, size_t ws_size,
                              hipStream_t stream) {
    const float* feats  = (const float*)d_in[0];
    const float* weight = (const float*)d_in[1];
    const float* gamma  = (const float*)d_in[2];
    const float* beta   = (const float*)d_in[3];
    const int*   in_idx = (const int*)d_in[4];
    const int*   out_idx= (const int*)d_in[5];
    float* out   = (float*)d_out;
    float* stats = (float*)d_ws;

    int n4 = out_size / 4;                 // 4.8M float4
    int zb = (n4 + 255) / 256;

    zero_kernel<<<zb, 256, 0, stream>>>((float4*)out, n4, stats);
    conv_kernel<<<KOFF * BLOCKS_PER_K, 256, 0, stream>>>(feats, weight, in_idx, out_idx, out);
    stats_kernel<<<2048, 256, 0, stream>>>((const float4*)out, stats);
    norm_kernel<<<zb, 256, 0, stream>>>((float4*)out, n4, stats, gamma, beta);
}